// Round 14
// baseline (16.342 us; speedup 1.0000x reference)
//
#include <hip/hip_runtime.h>

// DIN scorer, fused, 4 b/block, DMA-staged goods + SPLIT-BARRIER pipeline:
//   R13 + T3/T4 counted-vmcnt: goods split half1 (rows 0..127/b, 64KB, feeds
//   tiles t=0,1) / half2 (rows 128..199/b, 36KB, feeds t=2,3). Stream waves
//   issue half1 THEN half2; barrier#1 is raw s_barrier preceded by
//   s_waitcnt vmcnt(4) (their half2 count; in-order retirement => half1 done)
//   -> half2 stays in flight ACROSS the barrier while all waves compute t01.
//   barrier#2 (vmcnt(0)) releases t23. Tests whether the post-stream serial
//   MFMA/sigmoid tail was exposed (R11 == R13 == 15.3us suggests either this
//   or an external wall).
//   Fences: sched_barrier(0) + memory clobbers around every waitcnt/barrier
//   (rule #18); b2 force-materialized before DMA issue so stream waves'
//   vmcnt holds ONLY the 12 DMAs. Arithmetic identical to R13 -> absmax 0.25.

#define BB 1024
#define BPB 4
#define NN 200
#define KK 32
#define HID 36
#define QP 40
#define LOG2E 1.44269504f

#define QBYTES (BPB * NN * KK * 4)       // 102400 staged goods bytes
#define VOFF   QBYTES                    // V16: 4 x 1920 shorts = 15360 B
#define COFF   (VOFF + 15360)            // c48: 192 floats
#define WOFF   (COFF + 768)              // w248: 48 floats
#define ROFF   (WOFF + 192)              // red_s: 512 floats
#define SMEM_TOTAL (ROFF + 2048)         // 120768 B

typedef __attribute__((ext_vector_type(8))) short bf16x8;
typedef __attribute__((ext_vector_type(4))) float f32x4;

__device__ __forceinline__ float rfl(float x) {
    return __uint_as_float(__builtin_amdgcn_readfirstlane(__float_as_uint(x)));
}
__device__ __forceinline__ unsigned short f2bf(float x) {   // RNE f32->bf16
    unsigned int u = __float_as_uint(x);
    u = (u + 0x7fffu + ((u >> 16) & 1u)) >> 16;
    return (unsigned short)u;
}
__device__ __forceinline__ unsigned int pk_bf16(float lo, float hi) { // RNE pack
    unsigned int r;
    asm("v_cvt_pk_bf16_f32 %0, %1, %2" : "=v"(r) : "v"(lo), "v"(hi));
    return r;
}
__device__ __forceinline__ float fast_rcp(float x) {
#if __has_builtin(__builtin_amdgcn_rcpf)
    return __builtin_amdgcn_rcpf(x);
#else
    return 1.0f / x;
#endif
}
__device__ __forceinline__ float fast_exp2(float x) {
#if __has_builtin(__builtin_amdgcn_exp2f)
    return __builtin_amdgcn_exp2f(x);
#else
    return exp2f(x);
#endif
}

__global__ __launch_bounds__(1024, 4) void din_kernel(
    const float* __restrict__ cad,    // [B,K]
    const float* __restrict__ goods,  // [B,N,K]
    const float* __restrict__ W1,     // [1088*36]
    const float* __restrict__ b1p,    // [36]
    const float* __restrict__ W2,     // [36]
    const float* __restrict__ b2p,    // [1]
    float* __restrict__ out)          // [B,K]
{
    extern __shared__ char smem[];
    char*           Qlds = smem;                                   // 102400 B, swizzled goods
    unsigned short* V16  = (unsigned short*)(smem + VOFF);         // [b][h*QP+j]
    float*          c48  = (float*)(smem + COFF);                  // -c*LOG2E padded
    float*          w248 = (float*)(smem + WOFF);                  // W2 padded
    float*          red_s = (float*)(smem + ROFF);

    const int tid  = threadIdx.x;
    const int b0   = blockIdx.x * BPB;
    const int lane = tid & 63;
    const int wv   = tid >> 6;           // 0..15
    const int l15  = lane & 15, lk = lane >> 4;
    const int bsel = wv & 3;             // this wave's b in the MFMA phase
    const int mrow = wv >> 2;            // base m-tile (0..3)

    // ---- b2 first, force-materialized so stream waves' vmcnt = DMAs only ----
    const float b2v = rfl(b2p[0]);
    asm volatile("" :: "s"(b2v));

    // ---- goods -> LDS DMA, waves 6..15; half1 (rows<128) then half2 ----
    // unit u (1KB = 8 rows): u = b*25 + local; half1 local 0..15, half2 16..24.
    if (wv >= 6) {
        const char* gsrc = (const char*)(goods + (size_t)b0 * NN * KK);
        const int loff = (lane * 16) ^ ((lane >> 3) << 4);
        const int si = wv - 6;                       // 0..9
        if (si < 8) {                                 // half1: waves 6..13, 8 units
            #pragma unroll
            for (int j = 0; j < 8; ++j) {
                const int g = si * 8 + j;             // 0..63
                const int u = (g >> 4) * 25 + (g & 15);
                __builtin_amdgcn_global_load_lds(
                    (const __attribute__((address_space(1))) void*)(gsrc + u * 1024 + loff),
                    (__attribute__((address_space(3))) void*)(Qlds + u * 1024),
                    16, 0, 0);
            }
        }
        if (si < 9) {                                 // half2: waves 6..14, 4 units
            #pragma unroll
            for (int j = 0; j < 4; ++j) {
                const int g = si * 4 + j;             // 0..35
                const int u = (g / 9) * 25 + 16 + (g % 9);
                __builtin_amdgcn_global_load_lds(
                    (const __attribute__((address_space(1))) void*)(gsrc + u * 1024 + loff),
                    (__attribute__((address_space(3))) void*)(Qlds + u * 1024),
                    16, 0, 0);
            }
        }
    }

    const float* k0p = cad + b0 * KK;    // uniform -> scalar loads
    const float* k1p = k0p + KK;
    const float* k2p = k1p + KK;
    const float* k3p = k2p + KK;

    // ---- Phase B: each W1 quad loaded ONCE, FMA'd for all 4 b's ----
    const float4* W1q = reinterpret_cast<const float4*>(W1);
    if (tid < 288) {
        float4 acc0 = W1q[288 + tid];                    // bias row (W1+1152)
        float4 acc1 = acc0, acc2 = acc0, acc3 = acc0;
        #pragma unroll 4
        for (int i = 0; i < KK; ++i) {
            const float4 w0 = W1q[576 + 288 * i + tid];
            const float ki0 = k0p[i], ki1 = k1p[i], ki2 = k2p[i], ki3 = k3p[i];
            acc0.x += ki0 * w0.x; acc0.y += ki0 * w0.y;
            acc0.z += ki0 * w0.z; acc0.w += ki0 * w0.w;
            acc1.x += ki1 * w0.x; acc1.y += ki1 * w0.y;
            acc1.z += ki1 * w0.z; acc1.w += ki1 * w0.w;
            acc2.x += ki2 * w0.x; acc2.y += ki2 * w0.y;
            acc2.z += ki2 * w0.z; acc2.w += ki2 * w0.w;
            acc3.x += ki3 * w0.x; acc3.y += ki3 * w0.y;
            acc3.z += ki3 * w0.z; acc3.w += ki3 * w0.w;
        }
        const float a0[4] = {acc0.x, acc0.y, acc0.z, acc0.w};
        const float a1[4] = {acc1.x, acc1.y, acc1.z, acc1.w};
        const float a2[4] = {acc2.x, acc2.y, acc2.z, acc2.w};
        const float a3[4] = {acc3.x, acc3.y, acc3.z, acc3.w};
        #pragma unroll
        for (int q = 0; q < 4; ++q) {
            const int e = 4 * tid + q, j = e / 36, h = e - 36 * j;
            const int o = h * QP + j;
            V16[0 * 1920 + o] = f2bf(a0[q]);
            V16[1 * 1920 + o] = f2bf(a1[q]);
            V16[2 * 1920 + o] = f2bf(a2[q]);
            V16[3 * 1920 + o] = f2bf(a3[q]);
        }
    } else if (tid < 324) {                              // 36 c-quads (4 b x 9)
        const int u = tid - 288, bl = u / 9, hq = u % 9;
        const float* kp = cad + (b0 + bl) * KK;
        float4 acc = reinterpret_cast<const float4*>(b1p)[hq];
        #pragma unroll 4
        for (int i = 0; i < KK; ++i) {
            const float ki = kp[i];
            const float4 wc = W1q[i * 9 + hq];           // W1[i*36 + 4*hq ..]
            acc.x += ki * wc.x; acc.y += ki * wc.y;
            acc.z += ki * wc.z; acc.w += ki * wc.w;
        }
        float4 cp4;
        cp4.x = -acc.x * LOG2E; cp4.y = -acc.y * LOG2E;
        cp4.z = -acc.z * LOG2E; cp4.w = -acc.w * LOG2E;
        *reinterpret_cast<float4*>(&c48[bl * 48 + 4 * hq]) = cp4;
    } else if (tid < 336) {                              // c pads (4 b x 3 quads)
        const int u = tid - 324, bl = u / 3, q = u % 3;
        *reinterpret_cast<float4*>(&c48[bl * 48 + 36 + 4 * q]) =
            make_float4(0.f, 0.f, 0.f, 0.f);
    } else if (tid < 348) {                              // w248: 9 copy + 3 pad
        const int u = tid - 336;
        if (u < 9)
            *reinterpret_cast<float4*>(&w248[4 * u]) =
                reinterpret_cast<const float4*>(W2)[u];
        else
            *reinterpret_cast<float4*>(&w248[36 + 4 * (u - 9)]) =
                make_float4(0.f, 0.f, 0.f, 0.f);
    } else if (tid < 732) {                              // V16 pad rows 36..47, 4 copies
        const int p = tid - 348;                         // 0..383
        const int word = p % 192, pair = p / 192;        // pair 0: copies 0,1; pair 1: 2,3
        const int w = (36 + (word >> 4)) * (QP / 2) + (word & 15);
        ((unsigned int*)V16)[(2 * pair + 0) * 960 + w] = 0u;
        ((unsigned int*)V16)[(2 * pair + 1) * 960 + w] = 0u;
    }

    // ---- barrier #1: half1 + V16/c48/w248 ready; half2 STAYS IN FLIGHT ----
    asm volatile("" ::: "memory");
    asm volatile("s_waitcnt vmcnt(4) lgkmcnt(0)" ::: "memory");
    __builtin_amdgcn_sched_barrier(0);
    __builtin_amdgcn_s_barrier();
    __builtin_amdgcn_sched_barrier(0);

    // ---- MFMA phase: wave wv -> b=bsel, m in {mrow+4t}; ALL reads from LDS ----
    bf16x8 bfr[3];
    #pragma unroll
    for (int nt = 0; nt < 3; ++nt)
        bfr[nt] = *reinterpret_cast<const bf16x8*>(
            V16 + bsel * 1920 + (nt * 16 + l15) * QP + lk * 8);
    const float* cb = c48 + bsel * 48;

    float facc[8] = {0.f, 0.f, 0.f, 0.f, 0.f, 0.f, 0.f, 0.f};

    auto tile = [&](const float4& qa, const float4& qb, int m, bool masked) {
        union { unsigned int u[4]; bf16x8 v; } aq;
        aq.u[0] = pk_bf16(qa.x, qa.y);
        aq.u[1] = pk_bf16(qa.z, qa.w);
        aq.u[2] = pk_bf16(qb.x, qb.y);
        aq.u[3] = pk_bf16(qb.z, qb.w);
        const f32x4 zero = {0.f, 0.f, 0.f, 0.f};
        const f32x4 d0 = __builtin_amdgcn_mfma_f32_16x16x32_bf16(bfr[0], aq.v, zero, 0, 0, 0);
        const f32x4 d1 = __builtin_amdgcn_mfma_f32_16x16x32_bf16(bfr[1], aq.v, zero, 0, 0, 0);
        const f32x4 d2 = __builtin_amdgcn_mfma_f32_16x16x32_bf16(bfr[2], aq.v, zero, 0, 0, 0);

        const f32x4 c0 = *reinterpret_cast<const f32x4*>(cb + lk * 4);
        const f32x4 w0 = *reinterpret_cast<const f32x4*>(&w248[lk * 4]);
        const f32x4 c1 = *reinterpret_cast<const f32x4*>(cb + 16 + lk * 4);
        const f32x4 w1 = *reinterpret_cast<const f32x4*>(&w248[16 + lk * 4]);
        const f32x4 c2 = *reinterpret_cast<const f32x4*>(cb + 32 + lk * 4);
        const f32x4 w2 = *reinterpret_cast<const f32x4*>(&w248[32 + lk * 4]);

        float p = 0.f;
        #pragma unroll
        for (int r = 0; r < 4; ++r) {
            p += fast_rcp(1.0f + fast_exp2(__builtin_fmaf(d0[r], -LOG2E, c0[r]))) * w0[r];
            p += fast_rcp(1.0f + fast_exp2(__builtin_fmaf(d1[r], -LOG2E, c1[r]))) * w1[r];
            p += fast_rcp(1.0f + fast_exp2(__builtin_fmaf(d2[r], -LOG2E, c2[r]))) * w2[r];
        }
        p += __shfl_xor(p, 16, 64);
        p += __shfl_xor(p, 32, 64);

        float wn = b2v + p;
        if (masked) {
            const int n = m * 16 + l15;
            wn = (n < NN) ? wn : 0.f;
        }
        facc[0] += qa.x * wn; facc[1] += qa.y * wn;
        facc[2] += qa.z * wn; facc[3] += qa.w * wn;
        facc[4] += qb.x * wn; facc[5] += qb.y * wn;
        facc[6] += qb.z * wn; facc[7] += qb.w * wn;
    };

    auto ldq = [&](int m, float4& qa, float4& qb) {
        int row = m * 16 + l15;
        row = (row < NN) ? row : (NN - 1);
        const int rlin  = bsel * NN + row;            // staged row index
        const int byte0 = rlin * 128 + lk * 32;
        const int swz   = (rlin & 7) << 4;            // same XOR as staging
        qa = *reinterpret_cast<const float4*>(Qlds + (byte0 ^ swz));
        qb = *reinterpret_cast<const float4*>(Qlds + ((byte0 + 16) ^ swz));
    };

    // tiles t=0,1 (rows < 128, half1) -- overlapped with half2 DMA in flight
    #pragma unroll
    for (int t = 0; t < 2; ++t) {
        const int m = mrow + 4 * t;                   // 0..7, unmasked
        float4 qa, qb;
        ldq(m, qa, qb);
        tile(qa, qb, m, false);
    }

    // ---- barrier #2: half2 (rows 128..199) landed ----
    asm volatile("" ::: "memory");
    asm volatile("s_waitcnt vmcnt(0)" ::: "memory");
    __builtin_amdgcn_sched_barrier(0);
    __builtin_amdgcn_s_barrier();
    __builtin_amdgcn_sched_barrier(0);

    // tiles t=2,3
    #pragma unroll
    for (int t = 2; t < 4; ++t) {
        const int m = mrow + 4 * t;
        if (m < 13) {
            float4 qa, qb;
            ldq(m, qa, qb);
            tile(qa, qb, m, m == 12);
        }
    }

    // ---- reduce facc over the 16 l15-lanes (cols lk*8..lk*8+7) ----
    #pragma unroll
    for (int s = 1; s <= 8; s <<= 1) {
        #pragma unroll
        for (int u = 0; u < 8; ++u)
            facc[u] += __shfl_xor(facc[u], s, 64);
    }
    if (l15 == 0) {
        #pragma unroll
        for (int u = 0; u < 8; ++u)
            red_s[(bsel * 4 + mrow) * KK + lk * 8 + u] = facc[u];
    }
    __syncthreads();

    if (tid < BPB * KK) {
        const int bl = tid >> 5, j = tid & 31;
        float s = 0.f;
        #pragma unroll
        for (int g = 0; g < 4; ++g) s += red_s[(bl * 4 + g) * KK + j];
        out[(b0 + bl) * KK + j] = s;
    }
}

extern "C" void kernel_launch(void* const* d_in, const int* in_sizes, int n_in,
                              void* d_out, int out_size, void* d_ws, size_t ws_size,
                              hipStream_t stream) {
    const float* cad   = (const float*)d_in[0];
    const float* goods = (const float*)d_in[1];
    const float* W1    = (const float*)d_in[2];
    const float* b1    = (const float*)d_in[3];
    const float* W2    = (const float*)d_in[4];
    const float* b2    = (const float*)d_in[5];
    float* outp = (float*)d_out;

    static bool attr_set = false;
    if (!attr_set) {
        (void)hipFuncSetAttribute((const void*)din_kernel,
                                  hipFuncAttributeMaxDynamicSharedMemorySize,
                                  SMEM_TOTAL);
        attr_set = true;
    }

    din_kernel<<<BB / BPB, 1024, SMEM_TOTAL, stream>>>(cad, goods, W1, b1, W2, b2, outp);
}

// Round 15
// 15.246 us; speedup vs baseline: 1.0719x; 1.0719x over previous
//
#include <hip/hip_runtime.h>

// DIN scorer, fused, 4 b/block, DMA-staged goods -- R13 + NON-TEMPORAL stream:
//   The harness's ~268MB poison fill (> 256MB L3) leaves the L3 full of DIRTY
//   lines. Default-policy goods reads miss L3 and evict dirty victims ->
//   one forced 128B writeback per 128B read -> effective stream BW ~2TB/s
//   (explains the schedule-invariant 15.3us floor of R11/R13/R14).
//   Fix: aux=2 (CPol NT, gfx94x/gfx950) on the global_load_lds DMAs --
//   goods has ZERO reuse (each block reads a disjoint slice once into LDS),
//   so no-allocate streaming is semantically ideal: no evictions, no
//   writebacks, stream at HBM read BW. W1/cad keep default policy (W1 IS
//   reused across the 32 CUs of each XCD).
//   Everything else identical to R13 (single-lever A/B): 1 block/CU, Phase B
//   W1-amortized 4x, zero-VGPR staging by waves 6..15, XOR-swizzled LDS,
//   single vmcnt(0) barrier. Numerics unchanged -> absmax 0.25.

#define BB 1024
#define BPB 4
#define NN 200
#define KK 32
#define HID 36
#define QP 40
#define LOG2E 1.44269504f

#define QBYTES (BPB * NN * KK * 4)       // 102400 staged goods bytes
#define VOFF   QBYTES                    // V16: 4 x 1920 shorts = 15360 B
#define COFF   (VOFF + 15360)            // c48: 192 floats
#define WOFF   (COFF + 768)              // w248: 48 floats
#define ROFF   (WOFF + 192)              // red_s: 512 floats
#define SMEM_TOTAL (ROFF + 2048)         // 120768 B

typedef __attribute__((ext_vector_type(8))) short bf16x8;
typedef __attribute__((ext_vector_type(4))) float f32x4;

__device__ __forceinline__ float rfl(float x) {
    return __uint_as_float(__builtin_amdgcn_readfirstlane(__float_as_uint(x)));
}
__device__ __forceinline__ unsigned short f2bf(float x) {   // RNE f32->bf16
    unsigned int u = __float_as_uint(x);
    u = (u + 0x7fffu + ((u >> 16) & 1u)) >> 16;
    return (unsigned short)u;
}
__device__ __forceinline__ unsigned int pk_bf16(float lo, float hi) { // RNE pack
    unsigned int r;
    asm("v_cvt_pk_bf16_f32 %0, %1, %2" : "=v"(r) : "v"(lo), "v"(hi));
    return r;
}
__device__ __forceinline__ float fast_rcp(float x) {
#if __has_builtin(__builtin_amdgcn_rcpf)
    return __builtin_amdgcn_rcpf(x);
#else
    return 1.0f / x;
#endif
}
__device__ __forceinline__ float fast_exp2(float x) {
#if __has_builtin(__builtin_amdgcn_exp2f)
    return __builtin_amdgcn_exp2f(x);
#else
    return exp2f(x);
#endif
}

__global__ __launch_bounds__(1024, 4) void din_kernel(
    const float* __restrict__ cad,    // [B,K]
    const float* __restrict__ goods,  // [B,N,K]
    const float* __restrict__ W1,     // [1088*36]
    const float* __restrict__ b1p,    // [36]
    const float* __restrict__ W2,     // [36]
    const float* __restrict__ b2p,    // [1]
    float* __restrict__ out)          // [B,K]
{
    extern __shared__ char smem[];
    char*           Qlds = smem;                                   // 102400 B, swizzled goods
    unsigned short* V16  = (unsigned short*)(smem + VOFF);         // [b][h*QP+j]
    float*          c48  = (float*)(smem + COFF);                  // -c*LOG2E padded
    float*          w248 = (float*)(smem + WOFF);                  // W2 padded
    float*          red_s = (float*)(smem + ROFF);

    const int tid  = threadIdx.x;
    const int b0   = blockIdx.x * BPB;
    const int lane = tid & 63;
    const int wv   = tid >> 6;           // 0..15
    const int l15  = lane & 15, lk = lane >> 4;
    const int bsel = wv & 3;             // this wave's b in the MFMA phase
    const int mrow = wv >> 2;            // base m-tile (0..3)

    // ---- goods -> LDS DMA, waves 6..15 only (10 x 1KB wave-units each) ----
    // NT policy (aux=2): no L2/L3 allocation -> no dirty-victim writebacks.
    // LDS stays linear (HW: base + lane*16); swizzle on the GLOBAL address.
    if (wv >= 6) {
        const char* gsrc = (const char*)(goods + (size_t)b0 * NN * KK);
        const int loff = (lane * 16) ^ ((lane >> 3) << 4);
        const int ubase = (wv - 6) * 10;
        #pragma unroll
        for (int j = 0; j < 10; ++j) {
            const int u = ubase + j;
            __builtin_amdgcn_global_load_lds(
                (const __attribute__((address_space(1))) void*)(gsrc + u * 1024 + loff),
                (__attribute__((address_space(3))) void*)(Qlds + u * 1024),
                16, 0, 2 /* CPol NT */);
        }
    }

    const float* k0p = cad + b0 * KK;    // uniform -> scalar loads
    const float* k1p = k0p + KK;
    const float* k2p = k1p + KK;
    const float* k3p = k2p + KK;
    const float b2v = rfl(b2p[0]);

    // ---- Phase B: each W1 quad loaded ONCE, FMA'd for all 4 b's ----
    const float4* W1q = reinterpret_cast<const float4*>(W1);
    if (tid < 288) {
        float4 acc0 = W1q[288 + tid];                    // bias row (W1+1152)
        float4 acc1 = acc0, acc2 = acc0, acc3 = acc0;
        #pragma unroll 4
        for (int i = 0; i < KK; ++i) {
            const float4 w0 = W1q[576 + 288 * i + tid];
            const float ki0 = k0p[i], ki1 = k1p[i], ki2 = k2p[i], ki3 = k3p[i];
            acc0.x += ki0 * w0.x; acc0.y += ki0 * w0.y;
            acc0.z += ki0 * w0.z; acc0.w += ki0 * w0.w;
            acc1.x += ki1 * w0.x; acc1.y += ki1 * w0.y;
            acc1.z += ki1 * w0.z; acc1.w += ki1 * w0.w;
            acc2.x += ki2 * w0.x; acc2.y += ki2 * w0.y;
            acc2.z += ki2 * w0.z; acc2.w += ki2 * w0.w;
            acc3.x += ki3 * w0.x; acc3.y += ki3 * w0.y;
            acc3.z += ki3 * w0.z; acc3.w += ki3 * w0.w;
        }
        const float a0[4] = {acc0.x, acc0.y, acc0.z, acc0.w};
        const float a1[4] = {acc1.x, acc1.y, acc1.z, acc1.w};
        const float a2[4] = {acc2.x, acc2.y, acc2.z, acc2.w};
        const float a3[4] = {acc3.x, acc3.y, acc3.z, acc3.w};
        #pragma unroll
        for (int q = 0; q < 4; ++q) {
            const int e = 4 * tid + q, j = e / 36, h = e - 36 * j;
            const int o = h * QP + j;
            V16[0 * 1920 + o] = f2bf(a0[q]);
            V16[1 * 1920 + o] = f2bf(a1[q]);
            V16[2 * 1920 + o] = f2bf(a2[q]);
            V16[3 * 1920 + o] = f2bf(a3[q]);
        }
    } else if (tid < 324) {                              // 36 c-quads (4 b x 9)
        const int u = tid - 288, bl = u / 9, hq = u % 9;
        const float* kp = cad + (b0 + bl) * KK;
        float4 acc = reinterpret_cast<const float4*>(b1p)[hq];
        #pragma unroll 4
        for (int i = 0; i < KK; ++i) {
            const float ki = kp[i];
            const float4 wc = W1q[i * 9 + hq];           // W1[i*36 + 4*hq ..]
            acc.x += ki * wc.x; acc.y += ki * wc.y;
            acc.z += ki * wc.z; acc.w += ki * wc.w;
        }
        float4 cp4;
        cp4.x = -acc.x * LOG2E; cp4.y = -acc.y * LOG2E;
        cp4.z = -acc.z * LOG2E; cp4.w = -acc.w * LOG2E;
        *reinterpret_cast<float4*>(&c48[bl * 48 + 4 * hq]) = cp4;
    } else if (tid < 336) {                              // c pads (4 b x 3 quads)
        const int u = tid - 324, bl = u / 3, q = u % 3;
        *reinterpret_cast<float4*>(&c48[bl * 48 + 36 + 4 * q]) =
            make_float4(0.f, 0.f, 0.f, 0.f);
    } else if (tid < 348) {                              // w248: 9 copy + 3 pad
        const int u = tid - 336;
        if (u < 9)
            *reinterpret_cast<float4*>(&w248[4 * u]) =
                reinterpret_cast<const float4*>(W2)[u];
        else
            *reinterpret_cast<float4*>(&w248[36 + 4 * (u - 9)]) =
                make_float4(0.f, 0.f, 0.f, 0.f);
    } else if (tid < 732) {                              // V16 pad rows 36..47, 4 copies
        const int p = tid - 348;                         // 0..383
        const int word = p % 192, pair = p / 192;        // pair 0: copies 0,1; pair 1: 2,3
        const int w = (36 + (word >> 4)) * (QP / 2) + (word & 15);
        ((unsigned int*)V16)[(2 * pair + 0) * 960 + w] = 0u;
        ((unsigned int*)V16)[(2 * pair + 1) * 960 + w] = 0u;
    }
    __syncthreads();   // vmcnt(0) drains the DMA; V16/c48/w248/Qlds all ready

    // ---- MFMA phase: wave wv -> b=bsel, m in {mrow+4t}; ALL reads from LDS ----
    bf16x8 bfr[3];
    #pragma unroll
    for (int nt = 0; nt < 3; ++nt)
        bfr[nt] = *reinterpret_cast<const bf16x8*>(
            V16 + bsel * 1920 + (nt * 16 + l15) * QP + lk * 8);
    const float* cb = c48 + bsel * 48;

    float facc[8] = {0.f, 0.f, 0.f, 0.f, 0.f, 0.f, 0.f, 0.f};

    auto tile = [&](const float4& qa, const float4& qb, int m, bool masked) {
        union { unsigned int u[4]; bf16x8 v; } aq;
        aq.u[0] = pk_bf16(qa.x, qa.y);
        aq.u[1] = pk_bf16(qa.z, qa.w);
        aq.u[2] = pk_bf16(qb.x, qb.y);
        aq.u[3] = pk_bf16(qb.z, qb.w);
        const f32x4 zero = {0.f, 0.f, 0.f, 0.f};
        const f32x4 d0 = __builtin_amdgcn_mfma_f32_16x16x32_bf16(bfr[0], aq.v, zero, 0, 0, 0);
        const f32x4 d1 = __builtin_amdgcn_mfma_f32_16x16x32_bf16(bfr[1], aq.v, zero, 0, 0, 0);
        const f32x4 d2 = __builtin_amdgcn_mfma_f32_16x16x32_bf16(bfr[2], aq.v, zero, 0, 0, 0);

        const f32x4 c0 = *reinterpret_cast<const f32x4*>(cb + lk * 4);
        const f32x4 w0 = *reinterpret_cast<const f32x4*>(&w248[lk * 4]);
        const f32x4 c1 = *reinterpret_cast<const f32x4*>(cb + 16 + lk * 4);
        const f32x4 w1 = *reinterpret_cast<const f32x4*>(&w248[16 + lk * 4]);
        const f32x4 c2 = *reinterpret_cast<const f32x4*>(cb + 32 + lk * 4);
        const f32x4 w2 = *reinterpret_cast<const f32x4*>(&w248[32 + lk * 4]);

        float p = 0.f;
        #pragma unroll
        for (int r = 0; r < 4; ++r) {
            p += fast_rcp(1.0f + fast_exp2(__builtin_fmaf(d0[r], -LOG2E, c0[r]))) * w0[r];
            p += fast_rcp(1.0f + fast_exp2(__builtin_fmaf(d1[r], -LOG2E, c1[r]))) * w1[r];
            p += fast_rcp(1.0f + fast_exp2(__builtin_fmaf(d2[r], -LOG2E, c2[r]))) * w2[r];
        }
        p += __shfl_xor(p, 16, 64);
        p += __shfl_xor(p, 32, 64);

        float wn = b2v + p;
        if (masked) {
            const int n = m * 16 + l15;
            wn = (n < NN) ? wn : 0.f;
        }
        facc[0] += qa.x * wn; facc[1] += qa.y * wn;
        facc[2] += qa.z * wn; facc[3] += qa.w * wn;
        facc[4] += qb.x * wn; facc[5] += qb.y * wn;
        facc[6] += qb.z * wn; facc[7] += qb.w * wn;
    };

    #pragma unroll
    for (int t = 0; t < 4; ++t) {
        const int m = mrow + 4 * t;
        if (m < 13) {
            int row = m * 16 + l15;
            row = (row < NN) ? row : (NN - 1);
            const int rlin  = bsel * NN + row;            // staged row index
            const int byte0 = rlin * 128 + lk * 32;
            const int swz   = (rlin & 7) << 4;            // same XOR as staging
            const float4 qa = *reinterpret_cast<const float4*>(Qlds + (byte0 ^ swz));
            const float4 qb = *reinterpret_cast<const float4*>(Qlds + ((byte0 + 16) ^ swz));
            tile(qa, qb, m, m == 12);
        }
    }

    // ---- reduce facc over the 16 l15-lanes (cols lk*8..lk*8+7) ----
    #pragma unroll
    for (int s = 1; s <= 8; s <<= 1) {
        #pragma unroll
        for (int u = 0; u < 8; ++u)
            facc[u] += __shfl_xor(facc[u], s, 64);
    }
    if (l15 == 0) {
        #pragma unroll
        for (int u = 0; u < 8; ++u)
            red_s[(bsel * 4 + mrow) * KK + lk * 8 + u] = facc[u];
    }
    __syncthreads();

    if (tid < BPB * KK) {
        const int bl = tid >> 5, j = tid & 31;
        float s = 0.f;
        #pragma unroll
        for (int g = 0; g < 4; ++g) s += red_s[(bl * 4 + g) * KK + j];
        out[(b0 + bl) * KK + j] = s;
    }
}

extern "C" void kernel_launch(void* const* d_in, const int* in_sizes, int n_in,
                              void* d_out, int out_size, void* d_ws, size_t ws_size,
                              hipStream_t stream) {
    const float* cad   = (const float*)d_in[0];
    const float* goods = (const float*)d_in[1];
    const float* W1    = (const float*)d_in[2];
    const float* b1    = (const float*)d_in[3];
    const float* W2    = (const float*)d_in[4];
    const float* b2    = (const float*)d_in[5];
    float* outp = (float*)d_out;

    static bool attr_set = false;
    if (!attr_set) {
        (void)hipFuncSetAttribute((const void*)din_kernel,
                                  hipFuncAttributeMaxDynamicSharedMemorySize,
                                  SMEM_TOTAL);
        attr_set = true;
    }

    din_kernel<<<BB / BPB, 1024, SMEM_TOTAL, stream>>>(cad, goods, W1, b1, W2, b2, outp);
}